// Round 4
// baseline (92.313 us; speedup 1.0000x reference)
//
#include <hip/hip_runtime.h>
#include <math.h>

// One block per image (B blocks, 256 threads). Thread p<196 simulates the
// 4-qubit circuit for patch p entirely in registers (16 complex amps).
// v4 = v3 with measurement cross-term factor-2 fix:
//  - circuit RY C U0 RY C U1 RY C U2 -> initRY C V0 C V1 C measure(U2)
//    where V_l = RY(a_w)*U_l (SU(2) product, built per-thread, 8 FMA/wire)
//  - last layer folded into measurement: <Z_w> = <psi|U_w^dag Z U_w|psi>.
//    M=[[z,m],[mbar,-z]], z=|u0|^2-|u1|^2, m=2*conj(u0)*u1.
//    <pair> = z(|A|^2-|B|^2) + 2*Re(m*conj(A)*B)  -> store 2*Re(m), 2*Im(m).

// Apply SU(2) [[u0,u1],[-conj(u1),conj(u0)]] on qubit with stride ST.
#define APPLY_U(ST, U0R, U0I, U1R, U1I) do { \
  _Pragma("unroll") \
  for (int i = 0; i < 16; ++i) { \
    if (!(i & (ST))) { \
      float ar = sr[i], ai = si[i], br = sr[i + (ST)], bi = si[i + (ST)]; \
      sr[i]        =  (U0R) * ar - (U0I) * ai + (U1R) * br - (U1I) * bi; \
      si[i]        =  (U0R) * ai + (U0I) * ar + (U1R) * bi + (U1I) * br; \
      sr[i + (ST)] = -(U1R) * ar - (U1I) * ai + (U0R) * br + (U0I) * bi; \
      si[i + (ST)] = -(U1R) * ai + (U1I) * ar + (U0R) * bi - (U0I) * br; \
    } } } while (0)

// V = RY(c,s) * U  (still SU(2)): v0 = c*u0 + s*conj(u1); v1 = c*u1 - s*conj(u0)
#define APPLY_V(ST, l, w) do { \
  const float* u_ = &uu[((l) * 4 + (w)) * 4]; \
  float u0r = u_[0], u0i = u_[1], u1r = u_[2], u1i = u_[3]; \
  float v0r = dc[w] * u0r + ds[w] * u1r; \
  float v0i = dc[w] * u0i - ds[w] * u1i; \
  float v1r = dc[w] * u1r - ds[w] * u0r; \
  float v1i = dc[w] * u1i + ds[w] * u0i; \
  APPLY_U(ST, v0r, v0i, v1r, v1i); \
} while (0)

#define APPLY_CNOT(SC, ST) do { \
  _Pragma("unroll") \
  for (int i = 0; i < 16; ++i) { \
    if ((i & (SC)) && !(i & (ST))) { \
      float tr = sr[i], ti = si[i]; \
      sr[i] = sr[i + (ST)]; si[i] = si[i + (ST)]; \
      sr[i + (ST)] = tr;    si[i + (ST)] = ti; \
    } } } while (0)

#define CNOT_RING() do { \
  APPLY_CNOT(8, 4); APPLY_CNOT(4, 2); APPLY_CNOT(2, 1); APPLY_CNOT(1, 8); \
} while (0)

template <int LC>   // LC = compile-time layer count; 0 = runtime loop
__global__ __launch_bounds__(256, 4) void quanv_fused_kernel(
    const float* __restrict__ x,    // (B,1,28,28)
    const float* __restrict__ qp,   // (L,4,3)
    const float* __restrict__ W,    // (10,784) row-major
    const float* __restrict__ bias, // (10,)
    float* __restrict__ out,        // (B,10)
    int Lrt)
{
  const int L = (LC > 0) ? LC : Lrt;
  const int n   = blockIdx.x;
  const int tid = threadIdx.x;
  const int p   = tid;            // patch index within image

  // uu: layers 0..L-2 fused-U inputs; mm: last-layer measurement constants.
  __shared__ float uu[8 * 16];    // [l*4+w]*4 -> u0r,u0i,u1r,u1i
  __shared__ float mm[4][3];      // per wire: z, 2*Re(m), 2*Im(m)
  if (tid < 4 * L) {
    const int l = tid >> 2, w = tid & 3;
    const float p0 = qp[l * 12 + w * 3 + 0];
    const float p1 = qp[l * 12 + w * 3 + 1];
    const float p2 = qp[l * 12 + w * 3 + 2];
    float c, s, ca, sa, cb, sb;
    __sincosf(0.5f * p1, &s, &c);
    __sincosf(0.5f * (p0 + p2), &sa, &ca);
    __sincosf(0.5f * (p0 - p2), &sb, &cb);
    const float u0r =  c * ca, u0i = -c * sa;
    const float u1r = -s * cb, u1i = -s * sb;
    if (l == L - 1) {
      mm[w][0] = (u0r * u0r + u0i * u0i) - (u1r * u1r + u1i * u1i);   // z
      mm[w][1] = 4.0f * (u0r * u1r + u0i * u1i);   // 2*Re(m), m=2*conj(u0)*u1
      mm[w][2] = 4.0f * (u0r * u1i - u0i * u1r);   // 2*Im(m)
    } else {
      float* u_ = &uu[(l * 4 + w) * 4];
      u_[0] = u0r; u_[1] = u0i; u_[2] = u1r; u_[3] = u1i;
    }
  }
  __syncthreads();

  float ez[4] = {0.f, 0.f, 0.f, 0.f};

  if (p < 196) {
    const int pr = p / 14, pcc = p % 14;
    const float2* xb = (const float2*)(x + (size_t)n * 784 + (2 * pr) * 28 + 2 * pcc);
    float2 top = xb[0], bot = xb[14];   // row stride 28 floats = 14 float2
    float dc[4], ds[4];
    __sincosf(0.5f * top.x, &ds[0], &dc[0]);
    __sincosf(0.5f * top.y, &ds[1], &dc[1]);
    __sincosf(0.5f * bot.x, &ds[2], &dc[2]);
    __sincosf(0.5f * bot.y, &ds[3], &dc[3]);

    float sr[16], si[16];

    // Init: data-RY on |0000> is a real product state.
    {
      float hi[4] = {dc[0] * dc[1], dc[0] * ds[1], ds[0] * dc[1], ds[0] * ds[1]};
      float lo[4] = {dc[2] * dc[3], dc[2] * ds[3], ds[2] * dc[3], ds[2] * ds[3]};
#pragma unroll
      for (int i = 0; i < 16; ++i) { sr[i] = hi[i >> 2] * lo[i & 3]; si[i] = 0.f; }
    }
    CNOT_RING();

    // Middle layers: V_l = RY(data)*U_l, then CNOT ring.
    if (LC > 0) {
#pragma unroll
      for (int l = 0; l < ((LC > 0) ? LC - 1 : 0); ++l) {
        APPLY_V(8, l, 0); APPLY_V(4, l, 1); APPLY_V(2, l, 2); APPLY_V(1, l, 3);
        CNOT_RING();
      }
    } else {
      for (int l = 0; l < L - 1; ++l) {
        APPLY_V(8, l, 0); APPLY_V(4, l, 1); APPLY_V(2, l, 2); APPLY_V(1, l, 3);
        CNOT_RING();
      }
    }

    // Measure: <Z_w> = z*sum(|A|^2-|B|^2) + 2Re(m)*sum(Re(conj(A)B)) - 2Im(m)*sum(Im(conj(A)B))
    float pp[16];
#pragma unroll
    for (int i = 0; i < 16; ++i) pp[i] = sr[i] * sr[i] + si[i] * si[i];
#pragma unroll
    for (int w = 0; w < 4; ++w) {
      const int st = 8 >> w;
      float zs = 0.f, re = 0.f, im = 0.f;
#pragma unroll
      for (int i = 0; i < 16; ++i) {
        if (!(i & st)) {
          zs += pp[i] - pp[i + st];
          re += sr[i] * sr[i + st] + si[i] * si[i + st];
          im += sr[i] * si[i + st] - si[i] * sr[i + st];
        }
      }
      ez[w] = mm[w][0] * zs + mm[w][1] * re - mm[w][2] * im;
    }
  }

  // Per-patch partial logits: feats[4p+w] * W[c, 4p+w]; W row base is 16B aligned.
  float part[10];
#pragma unroll
  for (int c = 0; c < 10; ++c) part[c] = 0.f;
  if (p < 196) {
    const float4* Wv = (const float4*)W;
#pragma unroll
    for (int c = 0; c < 10; ++c) {
      float4 wc = Wv[c * 196 + p];
      part[c] = ez[0] * wc.x + ez[1] * wc.y + ez[2] * wc.z + ez[3] * wc.w;
    }
  }

  // Reduce across the block: wave64 shuffle, then combine 4 waves in LDS.
  const int lane = tid & 63;
  const int wave = tid >> 6;
  __shared__ float red[4][10];
#pragma unroll
  for (int c = 0; c < 10; ++c) {
    float v = part[c];
#pragma unroll
    for (int off = 32; off > 0; off >>= 1) v += __shfl_down(v, off, 64);
    if (lane == 0) red[wave][c] = v;
  }
  __syncthreads();

  if (tid == 0) {
    float logits[10];
    float m = -1e30f;
#pragma unroll
    for (int c = 0; c < 10; ++c) {
      logits[c] = red[0][c] + red[1][c] + red[2][c] + red[3][c] + bias[c];
      m = fmaxf(m, logits[c]);
    }
    float sum = 0.f;
#pragma unroll
    for (int c = 0; c < 10; ++c) sum += __expf(logits[c] - m);
    float lse = m + __logf(sum);
#pragma unroll
    for (int c = 0; c < 10; ++c) out[(size_t)n * 10 + c] = logits[c] - lse;
  }
}

extern "C" void kernel_launch(void* const* d_in, const int* in_sizes, int n_in,
                              void* d_out, int out_size, void* d_ws, size_t ws_size,
                              hipStream_t stream) {
  const float* x    = (const float*)d_in[0];
  const float* qp   = (const float*)d_in[1];
  const float* W    = (const float*)d_in[2];
  const float* bias = (const float*)d_in[3];
  float* out        = (float*)d_out;

  const int B = in_sizes[0] / 784;   // images
  const int L = in_sizes[1] / 12;    // layers

  switch (L) {
    case 1: quanv_fused_kernel<1><<<B, 256, 0, stream>>>(x, qp, W, bias, out, L); break;
    case 2: quanv_fused_kernel<2><<<B, 256, 0, stream>>>(x, qp, W, bias, out, L); break;
    case 3: quanv_fused_kernel<3><<<B, 256, 0, stream>>>(x, qp, W, bias, out, L); break;
    case 4: quanv_fused_kernel<4><<<B, 256, 0, stream>>>(x, qp, W, bias, out, L); break;
    default: quanv_fused_kernel<0><<<B, 256, 0, stream>>>(x, qp, W, bias, out, L); break;
  }
}